// Round 3
// baseline (1892.237 us; speedup 1.0000x reference)
//
#include <hip/hip_runtime.h>

#define BB 1024
#define TT 1024
#define HH 64

// One block per (batch, direction). Thread j in [0,256) owns z-row j
// (gate = j>>6: 0=i, 1=f, 2=g(tanh), 3=o) and keeps Whh row j (64 f32) in
// VGPRs. h lives in LDS (double-buffered); wave 0 owns c and the FC dot.
__global__ __launch_bounds__(256, 4) void bilstm_kernel(
    const float* __restrict__ x,
    const float* __restrict__ Wih_f, const float* __restrict__ Whh_f,
    const float* __restrict__ bih_f, const float* __restrict__ bhh_f,
    const float* __restrict__ Wih_b, const float* __restrict__ Whh_b,
    const float* __restrict__ bih_b, const float* __restrict__ bhh_b,
    const float* __restrict__ fc_w, const float* __restrict__ fc_b,
    float* __restrict__ out)
{
    const int b    = blockIdx.x >> 1;
    const int dir  = blockIdx.x & 1;
    const int j    = threadIdx.x;
    const int gate = j >> 6;

    const float* __restrict__ Whh = dir ? Whh_b : Whh_f;
    const float* __restrict__ Wih = dir ? Wih_b : Wih_f;
    const float* __restrict__ bih = dir ? bih_b : bih_f;
    const float* __restrict__ bhh = dir ? bhh_b : bhh_f;

    __shared__ float xrow[TT];
    __shared__ float h_sh[2][HH];
    __shared__ float gsh[256];

    // Stage this batch's x row (4 KB) once; per-step reads become LDS broadcasts.
    for (int t = j; t < TT; t += 256) xrow[t] = x[(size_t)b * TT + t];

    // Whh row j -> registers (static indexing only).
    float w[HH];
#pragma unroll
    for (int k4 = 0; k4 < HH / 4; ++k4) {
        const float4 v = *reinterpret_cast<const float4*>(Whh + j * HH + 4 * k4);
        w[4 * k4 + 0] = v.x; w[4 * k4 + 1] = v.y;
        w[4 * k4 + 2] = v.z; w[4 * k4 + 3] = v.w;
    }
    const float wih  = Wih[j];
    const float bias = bih[j] + bhh[j];

    float c = 0.0f, fcw = 0.0f, fcb = 0.0f;
    if (j < HH) {
        h_sh[0][j] = 0.0f;
        fcw = fc_w[dir * HH + j];
        fcb = dir ? 0.0f : fc_b[0];
    }
    __syncthreads();

    float* __restrict__ outb = out + (size_t)b * TT;

    int cur = 0;
#pragma unroll 1
    for (int t = 0; t < TT; ++t) {
        // Reference quirk: bwd consumes x[T-1-t] but contributes to out[b, t].
        const float xt = xrow[dir ? (TT - 1 - t) : t];

        float z0 = fmaf(xt, wih, bias), z1 = 0.f, z2 = 0.f, z3 = 0.f;
#pragma unroll
        for (int k4 = 0; k4 < HH / 4; ++k4) {
            const float4 hv = *reinterpret_cast<const float4*>(&h_sh[cur][4 * k4]);
            z0 = fmaf(w[4 * k4 + 0], hv.x, z0);
            z1 = fmaf(w[4 * k4 + 1], hv.y, z1);
            z2 = fmaf(w[4 * k4 + 2], hv.z, z2);
            z3 = fmaf(w[4 * k4 + 3], hv.w, z3);
        }
        const float z = (z0 + z1) + (z2 + z3);

        // Wave-uniform branch (gate is constant per wave): no divergence.
        float a;
        if (gate == 2) a = 1.0f - 2.0f / (__expf(2.0f * z) + 1.0f);   // tanh
        else           a = 1.0f / (1.0f + __expf(-z));                 // sigmoid
        gsh[j] = a;
        __syncthreads();

        if (j < HH) {
            const float ai = gsh[j];
            const float af = gsh[64 + j];
            const float ag = gsh[128 + j];
            const float ao = gsh[192 + j];
            c = fmaf(af, c, ai * ag);
            const float th = 1.0f - 2.0f / (__expf(2.0f * c) + 1.0f);
            const float h  = ao * th;
            h_sh[cur ^ 1][j] = h;

            // Fused FC: out[b,t] += sum_l fc_w[dir*64+l] * h[l]  (+ fc_b once)
            float d = h * fcw;
#pragma unroll
            for (int off = 32; off; off >>= 1) d += __shfl_xor(d, off, 64);
            if (j == 0) atomicAdd(outb + t, d + fcb);
        }
        cur ^= 1;
        __syncthreads();
    }
}

extern "C" void kernel_launch(void* const* d_in, const int* in_sizes, int n_in,
                              void* d_out, int out_size, void* d_ws, size_t ws_size,
                              hipStream_t stream) {
    const float* xp    = (const float*)d_in[0];
    const float* Wih_f = (const float*)d_in[1];
    const float* Whh_f = (const float*)d_in[2];
    const float* bih_f = (const float*)d_in[3];
    const float* bhh_f = (const float*)d_in[4];
    const float* Wih_b = (const float*)d_in[5];
    const float* Whh_b = (const float*)d_in[6];
    const float* bih_b = (const float*)d_in[7];
    const float* bhh_b = (const float*)d_in[8];
    const float* fc_w  = (const float*)d_in[9];
    const float* fc_b  = (const float*)d_in[10];
    float* outp = (float*)d_out;

    // Both direction-blocks atomicAdd into out: zero it first (capture-safe).
    hipMemsetAsync(d_out, 0, (size_t)out_size * sizeof(float), stream);

    bilstm_kernel<<<dim3(BB * 2), dim3(256), 0, stream>>>(
        xp, Wih_f, Whh_f, bih_f, bhh_f,
        Wih_b, Whh_b, bih_b, bhh_b, fc_w, fc_b, outp);
}

// Round 4
// 1796.396 us; speedup vs baseline: 1.0534x; 1.0534x over previous
//
#include <hip/hip_runtime.h>

#define BB 1024
#define TT 1024
#define HH 64

#define LOG2E 1.44269504088896340736f

__device__ __forceinline__ float fast_sigmoid(float z) {
    // 1/(1+e^-z) via v_exp(2^x) + v_rcp: ~4 VALU ops, ~2 ulp.
    return __builtin_amdgcn_rcpf(1.0f + __builtin_amdgcn_exp2f(-z * LOG2E));
}
__device__ __forceinline__ float fast_tanh(float z) {
    // tanh(z) = 1 - 2/(e^{2z}+1)
    return fmaf(-2.0f, __builtin_amdgcn_rcpf(1.0f + __builtin_amdgcn_exp2f(2.0f * LOG2E * z)), 1.0f);
}

// One block per (batch, direction). Thread j in [0,256) owns z-row j
// (gate = j>>6: 0=i, 1=f, 2=g(tanh), 3=o). Whh row j lives in 16 NAMED
// float4 VGPR variables (R3 lesson: w[64] array -> compiler spilled it,
// VGPR_Count=44, WRITE_SIZE=64MB of scratch traffic). h double-buffered
// in LDS; wave 0 owns c and the fused FC dot.
__global__ __launch_bounds__(256, 4) void bilstm_kernel(
    const float* __restrict__ x,
    const float* __restrict__ Wih_f, const float* __restrict__ Whh_f,
    const float* __restrict__ bih_f, const float* __restrict__ bhh_f,
    const float* __restrict__ Wih_b, const float* __restrict__ Whh_b,
    const float* __restrict__ bih_b, const float* __restrict__ bhh_b,
    const float* __restrict__ fc_w, const float* __restrict__ fc_b,
    float* __restrict__ out)
{
    const int b    = blockIdx.x >> 1;
    const int dir  = blockIdx.x & 1;
    const int j    = threadIdx.x;
    const int gate = j >> 6;

    const float* __restrict__ Wih = dir ? Wih_b : Wih_f;
    const float* __restrict__ bih = dir ? bih_b : bih_f;
    const float* __restrict__ bhh = dir ? bhh_b : bhh_f;
    const float* __restrict__ Wrow = (dir ? Whh_b : Whh_f) + j * HH;

    __shared__ float xrow[TT];
    __shared__ float h_sh[2][HH];
    __shared__ float gsh[256];

    // Stage this batch's x row (4 KB) once; per-step reads become LDS broadcasts.
    for (int t = j; t < TT; t += 256) xrow[t] = x[(size_t)b * TT + t];

    // Whh row j -> 16 named float4s (all-static access: must registerize).
#define LDW(i) const float4 w##i = *reinterpret_cast<const float4*>(Wrow + 4 * (i));
    LDW(0)  LDW(1)  LDW(2)  LDW(3)  LDW(4)  LDW(5)  LDW(6)  LDW(7)
    LDW(8)  LDW(9)  LDW(10) LDW(11) LDW(12) LDW(13) LDW(14) LDW(15)
#undef LDW

    const float wih  = Wih[j];
    const float bias = bih[j] + bhh[j];

    float c = 0.0f, fcw = 0.0f, fcb = 0.0f;
    if (j < HH) {
        h_sh[0][j] = 0.0f;
        fcw = fc_w[dir * HH + j];
        fcb = dir ? 0.0f : fc_b[0];
    }
    __syncthreads();

    float* __restrict__ outb = out + (size_t)b * TT;

    float* ha = &h_sh[0][0];   // read buffer
    float* hb = &h_sh[1][0];   // write buffer

#pragma unroll 1
    for (int t = 0; t < TT; ++t) {
        // Reference quirk: bwd consumes x[T-1-t] but contributes to out[b, t].
        const float xt = xrow[dir ? (TT - 1 - t) : t];

        const float4* __restrict__ hv4 = reinterpret_cast<const float4*>(ha);
        float z0 = fmaf(xt, wih, bias), z1 = 0.f, z2 = 0.f, z3 = 0.f;
#define FMA4(i) { const float4 hv = hv4[i];                      \
        z0 = fmaf(w##i.x, hv.x, z0); z1 = fmaf(w##i.y, hv.y, z1); \
        z2 = fmaf(w##i.z, hv.z, z2); z3 = fmaf(w##i.w, hv.w, z3); }
        FMA4(0)  FMA4(1)  FMA4(2)  FMA4(3)  FMA4(4)  FMA4(5)  FMA4(6)  FMA4(7)
        FMA4(8)  FMA4(9)  FMA4(10) FMA4(11) FMA4(12) FMA4(13) FMA4(14) FMA4(15)
#undef FMA4
        const float z = (z0 + z1) + (z2 + z3);

        // Wave-uniform branch (gate constant per wave): no divergence.
        const float a = (gate == 2) ? fast_tanh(z) : fast_sigmoid(z);
        gsh[j] = a;
        __syncthreads();

        if (j < HH) {
            const float ai = gsh[j];
            const float af = gsh[64 + j];
            const float ag = gsh[128 + j];
            const float ao = gsh[192 + j];
            c = fmaf(af, c, ai * ag);
            const float h = ao * fast_tanh(c);
            hb[j] = h;

            // Fused FC: out[b,t] += sum_l fc_w[dir*64+l] * h[l]  (+ fc_b once)
            float d = h * fcw;
#pragma unroll
            for (int off = 32; off; off >>= 1) d += __shfl_xor(d, off, 64);
            if (j == 0) atomicAdd(outb + t, d + fcb);
        }
        float* tmp = ha; ha = hb; hb = tmp;
        __syncthreads();
    }
}

extern "C" void kernel_launch(void* const* d_in, const int* in_sizes, int n_in,
                              void* d_out, int out_size, void* d_ws, size_t ws_size,
                              hipStream_t stream) {
    const float* xp    = (const float*)d_in[0];
    const float* Wih_f = (const float*)d_in[1];
    const float* Whh_f = (const float*)d_in[2];
    const float* bih_f = (const float*)d_in[3];
    const float* bhh_f = (const float*)d_in[4];
    const float* Wih_b = (const float*)d_in[5];
    const float* Whh_b = (const float*)d_in[6];
    const float* bih_b = (const float*)d_in[7];
    const float* bhh_b = (const float*)d_in[8];
    const float* fc_w  = (const float*)d_in[9];
    const float* fc_b  = (const float*)d_in[10];
    float* outp = (float*)d_out;

    // Both direction-blocks atomicAdd into out: zero it first (capture-safe).
    hipMemsetAsync(d_out, 0, (size_t)out_size * sizeof(float), stream);

    bilstm_kernel<<<dim3(BB * 2), dim3(256), 0, stream>>>(
        xp, Wih_f, Whh_f, bih_f, bhh_f,
        Wih_b, Whh_b, bih_b, bhh_b, fc_w, fc_b, outp);
}

// Round 5
// 792.298 us; speedup vs baseline: 2.3883x; 2.2673x over previous
//
#include <hip/hip_runtime.h>

#define TT  1024
#define TCH 128

typedef __attribute__((ext_vector_type(8))) short short8;   // 8 bf16 = 4 VGPRs (MFMA A/B frag)
typedef __attribute__((ext_vector_type(4))) short short4v;  // 4 bf16 = 8B
typedef __attribute__((ext_vector_type(4))) float f32x4;    // MFMA C/D frag

#define LOG2E 1.44269504088896340736f

__device__ __forceinline__ float sigf(float z) {
    return __builtin_amdgcn_rcpf(1.0f + __builtin_amdgcn_exp2f(-z * LOG2E));
}
__device__ __forceinline__ float tanhf_(float z) {
    return fmaf(-2.0f, __builtin_amdgcn_rcpf(1.0f + __builtin_amdgcn_exp2f(2.0f * LOG2E * z)), 1.0f);
}
__device__ __forceinline__ short bhi(float f) {            // truncate f32 -> bf16 bits
    return (short)(__builtin_bit_cast(unsigned, f) >> 16);
}
__device__ __forceinline__ float fhi(float f) {            // f32 with mantissa low bits cleared
    return __builtin_bit_cast(float, __builtin_bit_cast(unsigned, f) & 0xffff0000u);
}

// One block per (8 sequences, 1 direction): 256 blocks = 1/CU. 4 waves.
// Wave w owns z M-tiles {w, w+4, w+8, w+12} = rows 16w..16w+15 of EACH gate,
// so each lane holds i,f,g,o for the same (h-row, seq): c/h update in-register.
// z = Whh*h via mfma_f32_16x16x32_bf16, hi/lo split (3 products).
// h crosses waves via a tiny double-buffered LDS tile ([seq][row], pad 72).
__global__ __launch_bounds__(256, 2) void bilstm_mfma(
    const float* __restrict__ x,
    const float* __restrict__ Wih_f, const float* __restrict__ Whh_f,
    const float* __restrict__ bih_f, const float* __restrict__ bhh_f,
    const float* __restrict__ Wih_b, const float* __restrict__ Whh_b,
    const float* __restrict__ bih_b, const float* __restrict__ bhh_b,
    const float* __restrict__ fc_w, const float* __restrict__ fc_b,
    float* __restrict__ out)
{
    const int dir = blockIdx.x & 1;
    const int b0  = (blockIdx.x >> 1) * 8;
    const int tid  = threadIdx.x;
    const int w    = tid >> 6;
    const int lane = tid & 63;
    const int hb   = lane >> 4;   // 16-lane group = K-chunk owner (A/B), row-group (C/D)
    const int n    = lane & 15;   // M row (A) / N col (B, C/D) = sequence

    const float* __restrict__ Whh = dir ? Whh_b : Whh_f;
    const float* __restrict__ Wih = dir ? Wih_b : Wih_f;
    const float* __restrict__ bih = dir ? bih_b : bih_f;
    const float* __restrict__ bhh = dir ? bhh_b : bhh_f;

    __shared__ short Hlds[2][2][16][72];   // [buf][hi/lo][seq][h-row], stride 144B (9x16B: aligned, 2-way max)
    __shared__ float xs[16][TCH + 1];      // stride 129 floats: conflict-free column read
    __shared__ float fcfb[2][16][4];       // [buf][seq][wave] FC partials

    // Zero H (both buffers) and the never-written xs rows 8..15.
    {
        unsigned* p1 = (unsigned*)&Hlds[0][0][0][0];
        for (int i = tid; i < 2 * 2 * 16 * 72 / 2; i += 256) p1[i] = 0u;
        float* p2 = &xs[8][0];
        for (int i = tid; i < 8 * (TCH + 1); i += 256) p2[i] = 0.f;
    }

    // A-fragments: Whh tile (M=16 z-rows, K=32 h-cols), lane holds
    // A[row = lane&15][k = 8*(lane>>4) + e], e=0..7. hi/lo bf16 split.
    short8 ahi[4][2], alo[4][2];
#pragma unroll
    for (int s = 0; s < 4; ++s)
#pragma unroll
        for (int kt = 0; kt < 2; ++kt) {
            const int zrow = 64 * s + 16 * w + n;       // M-tile mt = w + 4s
            const float* p = Whh + zrow * 64 + 32 * kt + 8 * hb;
            const float4 u0 = *(const float4*)p;
            const float4 u1 = *(const float4*)(p + 4);
            float v[8] = {u0.x, u0.y, u0.z, u0.w, u1.x, u1.y, u1.z, u1.w};
            short8 h8, l8;
#pragma unroll
            for (int e = 0; e < 8; ++e) {
                h8[e] = bhi(v[e]);
                l8[e] = bhi(v[e] - fhi(v[e]));
            }
            ahi[s][kt] = h8;
            alo[s][kt] = l8;
        }

    f32x4 biasv[4], wihv[4], fcwv;
#pragma unroll
    for (int s = 0; s < 4; ++s)
#pragma unroll
        for (int r = 0; r < 4; ++r) {
            const int row = 64 * s + 16 * w + 4 * hb + r;  // this lane's C/D rows
            biasv[s][r] = bih[row] + bhh[row];
            wihv[s][r]  = Wih[row];
        }
#pragma unroll
    for (int r = 0; r < 4; ++r) fcwv[r] = fc_w[dir * 64 + 16 * w + 4 * hb + r];
    const float fcbv = dir ? 0.f : fc_b[0];

    // Pin loop-invariant fragments into VGPRs. R3/R4 lesson: without this the
    // occupancy-chasing scheduler sinks the loads back into the t-loop
    // (VGPR_Count=44 both rounds despite 64 live weights).
    asm volatile("" : "+v"(ahi[0][0]), "+v"(ahi[0][1]), "+v"(ahi[1][0]), "+v"(ahi[1][1]),
                      "+v"(ahi[2][0]), "+v"(ahi[2][1]), "+v"(ahi[3][0]), "+v"(ahi[3][1]),
                      "+v"(alo[0][0]), "+v"(alo[0][1]), "+v"(alo[1][0]), "+v"(alo[1][1]),
                      "+v"(alo[2][0]), "+v"(alo[2][1]), "+v"(alo[3][0]), "+v"(alo[3][1]));
    asm volatile("" : "+v"(biasv[0]), "+v"(biasv[1]), "+v"(biasv[2]), "+v"(biasv[3]),
                      "+v"(wihv[0]), "+v"(wihv[1]), "+v"(wihv[2]), "+v"(wihv[3]), "+v"(fcwv));

    // First x tile (t = 0..TCH-1). Bwd consumes x reversed; out index stays t.
    for (int idx = tid; idx < 8 * TCH; idx += 256) {
        const int s = idx >> 7, i = idx & (TCH - 1);
        const int src = dir ? (TT - 1 - i) : i;
        xs[s][i] = x[(size_t)(b0 + s) * TT + src];
    }
    __syncthreads();

    f32x4 c = {0.f, 0.f, 0.f, 0.f};
    int cur = 0;

#pragma unroll 1
    for (int t = 0; t < TT; ++t) {
        if (t && (t & (TCH - 1)) == 0) {   // refill x tile (8x per kernel)
            for (int idx = tid; idx < 8 * TCH; idx += 256) {
                const int s = idx >> 7, i = idx & (TCH - 1);
                const int tg = t + i;
                const int src = dir ? (TT - 1 - tg) : tg;
                xs[s][i] = x[(size_t)(b0 + s) * TT + src];
            }
            __syncthreads();
        }
        // Drain previous step's FC partials (written before last barrier).
        if (t && w == 0 && lane < 8) {
            const float* fp = &fcfb[(t - 1) & 1][lane][0];
            atomicAdd(out + (size_t)(b0 + lane) * TT + (t - 1),
                      fp[0] + fp[1] + fp[2] + fp[3] + fcbv);
        }

        // B-fragments: H (K=32 h-rows, N=16 seqs): lane holds
        // B[k = 8*(lane>>4)+e][n = lane&15]. LDS [seq][row] -> 1 b128/frag.
        short8 Bf[2][2];
#pragma unroll
        for (int kt = 0; kt < 2; ++kt)
#pragma unroll
            for (int pp = 0; pp < 2; ++pp)
                Bf[kt][pp] = *(const short8*)&Hlds[cur][pp][n][32 * kt + 8 * hb];

        const float xt = xs[n][t & (TCH - 1)];

        f32x4 acc0, acc1, acc2, acc3;
#define ZCHAIN(ACC, S)                                                              \
        ACC[0] = fmaf(xt, wihv[S][0], biasv[S][0]);                                 \
        ACC[1] = fmaf(xt, wihv[S][1], biasv[S][1]);                                 \
        ACC[2] = fmaf(xt, wihv[S][2], biasv[S][2]);                                 \
        ACC[3] = fmaf(xt, wihv[S][3], biasv[S][3]);                                 \
        ACC = __builtin_amdgcn_mfma_f32_16x16x32_bf16(ahi[S][0], Bf[0][0], ACC, 0, 0, 0); \
        ACC = __builtin_amdgcn_mfma_f32_16x16x32_bf16(ahi[S][0], Bf[0][1], ACC, 0, 0, 0); \
        ACC = __builtin_amdgcn_mfma_f32_16x16x32_bf16(alo[S][0], Bf[0][0], ACC, 0, 0, 0); \
        ACC = __builtin_amdgcn_mfma_f32_16x16x32_bf16(ahi[S][1], Bf[1][0], ACC, 0, 0, 0); \
        ACC = __builtin_amdgcn_mfma_f32_16x16x32_bf16(ahi[S][1], Bf[1][1], ACC, 0, 0, 0); \
        ACC = __builtin_amdgcn_mfma_f32_16x16x32_bf16(alo[S][1], Bf[1][0], ACC, 0, 0, 0);
        ZCHAIN(acc0, 0)   // gate i
        ZCHAIN(acc1, 1)   // gate f
        ZCHAIN(acc2, 2)   // gate g
        ZCHAIN(acc3, 3)   // gate o
#undef ZCHAIN

        // Gates + state update, fully in-register (all 4 gates co-located per lane).
        f32x4 hnew;
        short4v ph, pl;
#pragma unroll
        for (int r = 0; r < 4; ++r) {
            const float gi = sigf(acc0[r]);
            const float gf = sigf(acc1[r]);
            const float gg = tanhf_(acc2[r]);
            const float go = sigf(acc3[r]);
            c[r] = fmaf(gf, c[r], gi * gg);
            const float hv = go * tanhf_(c[r]);
            hnew[r] = hv;
            ph[r] = bhi(hv);
            pl[r] = bhi(hv - fhi(hv));
        }
        const int nxt = cur ^ 1;
        *(short4v*)&Hlds[nxt][0][n][16 * w + 4 * hb] = ph;
        *(short4v*)&Hlds[nxt][1][n][16 * w + 4 * hb] = pl;

        // FC partial for this wave's 16 h-rows: reduce over hb groups.
        float d = hnew[0] * fcwv[0] + hnew[1] * fcwv[1] + hnew[2] * fcwv[2] + hnew[3] * fcwv[3];
        d += __shfl_xor(d, 16);
        d += __shfl_xor(d, 32);
        if (lane < 16) fcfb[t & 1][lane][w] = d;

        __syncthreads();
        cur = nxt;
    }

    // Final step's FC drain.
    if (w == 0 && lane < 8) {
        const float* fp = &fcfb[(TT - 1) & 1][lane][0];
        atomicAdd(out + (size_t)(b0 + lane) * TT + (TT - 1),
                  fp[0] + fp[1] + fp[2] + fp[3] + fcbv);
    }
}

extern "C" void kernel_launch(void* const* d_in, const int* in_sizes, int n_in,
                              void* d_out, int out_size, void* d_ws, size_t ws_size,
                              hipStream_t stream) {
    const float* xp    = (const float*)d_in[0];
    const float* Wih_f = (const float*)d_in[1];
    const float* Whh_f = (const float*)d_in[2];
    const float* bih_f = (const float*)d_in[3];
    const float* bhh_f = (const float*)d_in[4];
    const float* Wih_b = (const float*)d_in[5];
    const float* Whh_b = (const float*)d_in[6];
    const float* bih_b = (const float*)d_in[7];
    const float* bhh_b = (const float*)d_in[8];
    const float* fc_w  = (const float*)d_in[9];
    const float* fc_b  = (const float*)d_in[10];
    float* outp = (float*)d_out;

    // Both direction-blocks atomicAdd into out: zero it first (capture-safe).
    hipMemsetAsync(d_out, 0, (size_t)out_size * sizeof(float), stream);

    bilstm_mfma<<<dim3(256), dim3(256), 0, stream>>>(
        xp, Wih_f, Whh_f, bih_f, bhh_f,
        Wih_b, Whh_b, bih_b, bhh_b, fc_w, fc_b, outp);
}